// Round 23
// baseline (273.637 us; speedup 1.0000x reference)
//
#include <hip/hip_runtime.h>
#include <hip/hip_fp16.h>
#include <cstddef>

typedef _Float16 f16;
typedef __attribute__((ext_vector_type(8))) _Float16 f16x8;
typedef __attribute__((ext_vector_type(4))) _Float16 f16x4;
typedef __attribute__((ext_vector_type(2))) _Float16 f16x2;
typedef __attribute__((ext_vector_type(4))) float f32x4;
typedef __attribute__((ext_vector_type(16))) float f32x16;
typedef __attribute__((ext_vector_type(4))) unsigned int u32x4;
typedef unsigned int u32;

#define LOG2E 1.44269504088896340736f

typedef __attribute__((address_space(1))) const unsigned int gau32;
typedef __attribute__((address_space(3))) unsigned int lau32;

// ---------------- workspace layout (bytes) ----------------
#define OFF_NORM  0ull                                // 2 floats (sumsq q, sumsq k)
#define OFF_SLOTS 128ull                              // 64 slot-pairs (spread atomics), 512 B
#define OFF_WT    1024ull                             // f16 wt2[12ct][8ks][32ln][2hi][8] (wave-coalesced)
#define OFF_PWT   (OFF_WT + 384ull*128*2)             // f16 PWt[128][128] (proj_w transposed)
#define OFF_BIASP (OFF_PWT + 128ull*128*2)            // f16 bias2[4h][8g][8mt][32ln][2hi][16] (xLOG2E)
#define OFF_MASKP (OFF_BIASP + 4ull*256*256*2)        // f16 mask2[64w][8g][8mt][32ln][2hi][16] (xLOG2E)
#define OFF_QKV   (OFF_MASKP + 64ull*256*256*2)       // f16 q[1024][4][256][32] (-> overwritten by O), k same, vT[1024][4][32][256]
// end = OFF_QKV + 201,326,592 = 210,371,584 bytes (proven size)

#define QSZ 33554432ull   // elements per q/k/v section

// ---------------- K1: rel-pos bias MLP -> wave-coalesced f16 table (log2e-scaled) ----------------
// B2[h][g][mt][ln][hi][q]: g=n>>5, ln=n&31; m = mt*32 + rq*8 + hi*4 + i, q = rq*4+i.
__global__ void k_bias(const float* __restrict__ rel, const float* __restrict__ fc1w,
                       const float* __restrict__ fc1b, const float* __restrict__ fc2w,
                       const float* __restrict__ fc2b, f16* __restrict__ biasp) {
  int n = blockIdx.x, m = threadIdx.x;
  float r0 = rel[(n*256 + m)*2 + 0];
  float r1 = rel[(n*256 + m)*2 + 1];
  float a0 = fc2b[0], a1 = fc2b[1], a2 = fc2b[2], a3 = fc2b[3];
  for (int i = 0; i < 128; ++i) {
    float h = fmaf(r0, fc1w[i], fmaf(r1, fc1w[128 + i], fc1b[i]));
    float t = tanhf(0.7978845608028654f * (h + 0.044715f * h * h * h));
    float g = 0.5f * h * (1.0f + t);
    a0 = fmaf(g, fc2w[i*4 + 0], a0);
    a1 = fmaf(g, fc2w[i*4 + 1], a1);
    a2 = fmaf(g, fc2w[i*4 + 2], a2);
    a3 = fmaf(g, fc2w[i*4 + 3], a3);
  }
  int g = n >> 5, ln = n & 31;
  int mt = m >> 5, rem = m & 31;
  int rq = rem >> 3, hi = (rem >> 2) & 1, i = rem & 3;
  size_t base = (((size_t)(g*8 + mt)*32 + ln)*2 + hi)*16 + (rq*4 + i);
  biasp[0*65536 + base] = (f16)(a0 * LOG2E);
  biasp[1*65536 + base] = (f16)(a1 * LOG2E);
  biasp[2*65536 + base] = (f16)(a2 * LOG2E);
  biasp[3*65536 + base] = (f16)(a3 * LOG2E);
}

// ---------------- K2: weight transposes (fp32 -> fp16) ----------------
// wt2[(((ct*8+ks)*32+ln)*2+hi)*8 + j] = qkv_w[k][col], col=ct*32+ln, k=ks*16+hi*8+j
__global__ void k_transpose(const float* __restrict__ qkvw, const float* __restrict__ projw,
                            f16* __restrict__ wt, f16* __restrict__ pwt) {
  int idx = blockIdx.x*256 + threadIdx.x;        // 0..65535
  if (idx < 49152) {
    int col = idx >> 7, k = idx & 127;
    int ct = col >> 5, ln = col & 31;
    int ks = k >> 4, hi = (k >> 3) & 1, j = k & 7;
    wt[(((size_t)(ct*8 + ks)*32 + ln)*2 + hi)*8 + j] = (f16)qkvw[k*384 + col];
  } else {
    int p = idx - 49152;                         // PWt[col][k] = proj_w[k][col]
    int col = p >> 7, k = p & 127;
    pwt[p] = (f16)projw[k*128 + col];
  }
}

// ---------------- K3: mask fp32 -> wave-coalesced f16 (log2e-scaled) ----------------
// M2[w][g][mt][ln][hi][q]; thread t = (w, n, hi, mt) handles 16 outputs (rq,i).
__global__ void k_perm(const float* __restrict__ mask, f16* __restrict__ maskp) {
  int t = blockIdx.x*256 + threadIdx.x;          // 0..262143
  int mt = t & 7, hi = (t >> 3) & 1, n = (t >> 4) & 255, w = t >> 12;
  int g = n >> 5, ln = n & 31;
  const float* src = mask + (size_t)(w*256 + n)*256;
  f16* dst = maskp + (size_t)w*65536 + (((size_t)(g*8 + mt)*32 + ln)*2 + hi)*16;
  #pragma unroll
  for (int rq = 0; rq < 4; ++rq) {
    f32x4 v = *(const f32x4*)(src + mt*32 + rq*8 + hi*4);
    #pragma unroll
    for (int i = 0; i < 4; ++i) dst[rq*4 + i] = (f16)(v[i] * LOG2E);
  }
}

// ---------------- K4: QKV GEMM, 4096 blocks x 512 thr: 8 waves, wave = (row-half, ct-quarter of 3) ----------------
// wt loads 1KB-coalesced; q/k stores bounced through wave-private LDS tile [4 slot][32 row][16B]
// (conflict-free ds_writes, 2-way reads) -> 2 x 1KB coalesced global stores.
__global__ __launch_bounds__(512, 6)
void k_qkv(const float* __restrict__ x, const f16* __restrict__ wt,
           const float* __restrict__ qkvb, f16* __restrict__ qkv,
           float* __restrict__ slots) {
  __shared__ f16 xs[8192];      // stage [64 rows][128 k] swizzled; then 8 x 2KB wave bounce tiles
  int tid = threadIdx.x;
  int wv = tid >> 6, lane = tid & 63;
  int ln = lane & 31, hi = lane >> 5;

  // cooperative stage: 64x128 fp32 -> f16 LDS (swizzled), all 512 threads
  {
    const float* xt = x + (size_t)blockIdx.x*8192;
    char* xw = (char*)xs;
    #pragma unroll
    for (int it = 0; it < 4; ++it) {
      int idx = it*2048 + tid*4;                 // f32 elem index in 64x128 tile
      int rowl = idx >> 7, col = idx & 127;
      f32x4 v = *(const f32x4*)(xt + idx);
      f16x4 hv;
      #pragma unroll
      for (int j = 0; j < 4; ++j) hv[j] = (f16)v[j];
      *(f16x4*)(xw + rowl*256 + ((col*2) ^ ((rowl & 15) << 4))) = hv;
    }
  }
  __syncthreads();

  int rl = (wv >> 2)*32 + ln;                    // row within tile (0..63)
  int row = blockIdx.x*64 + rl;
  int b_ = row >> 8, n = row & 255;
  int ct0 = (wv & 3)*3;                          // ct quarter: 0-2, 3-5, 6-8, 9-11

  // read this lane's 8 B-frags (x[row=rl][k-slices])
  f16x8 xf[8];
  {
    const char* xw = (const char*)xs;
    #pragma unroll
    for (int ks = 0; ks < 8; ++ks)
      xf[ks] = *(const f16x8*)(xw + rl*256 + ((ks*32 + hi*16) ^ ((rl & 15) << 4)));
  }
  __syncthreads();   // xs frags consumed; regions become wave-private bounce buffers

  char* tb = (char*)xs + wv*2048;                // wave bounce tile: [4 slot][32 row][16B]
  int nb0 = blockIdx.x*64 + (wv >> 2)*32;        // first row of wave tile
  int b2 = nb0 >> 8, n2 = nb0 & 255;

  float sq = 0.f, sk = 0.f;
  #pragma unroll 1
  for (int cc = 0; cc < 3; ++cc) {
    int ct = ct0 + cc;
    f32x16 acc;
    #pragma unroll
    for (int g = 0; g < 4; ++g) {
      f32x4 qb = *(const f32x4*)(qkvb + ct*32 + g*8 + hi*4);
      #pragma unroll
      for (int i = 0; i < 4; ++i) acc[g*4 + i] = qb[i];
    }
    const f16* wbase = wt + (size_t)(ct*8)*512 + (ln*2 + hi)*8;
    #pragma unroll
    for (int ks = 0; ks < 8; ++ks) {
      f16x8 wf = *(const f16x8*)(wbase + ks*512);   // 1KB coalesced per instr
      acc = __builtin_amdgcn_mfma_f32_32x32x16_f16(wf, xf[ks], acc, 0, 0, 0);
    }
    int which = ct >> 2, hh = ct & 3;
    if (which == 0) {
      #pragma unroll
      for (int r = 0; r < 16; ++r) sq = fmaf(acc[r], acc[r], sq);
    } else if (which == 1) {
      #pragma unroll
      for (int r = 0; r < 16; ++r) sk = fmaf(acc[r], acc[r], sk);
    }
    if (which < 2) {   // q,k: bounce 32x32 tile through LDS -> 2 x 1KB coalesced stores
      #pragma unroll
      for (int g = 0; g < 4; ++g) {
        f16x4 pk;
        #pragma unroll
        for (int i = 0; i < 4; ++i) pk[i] = (f16)acc[g*4 + i];
        *(f16x4*)(tb + g*512 + ln*16 + hi*8) = pk;   // [slot g][row ln][hi*8]: conflict-free
      }
      f16* dst0 = qkv + (size_t)which*QSZ + ((size_t)(b2*4 + hh)*256 + n2)*32;
      #pragma unroll
      for (int it = 0; it < 2; ++it) {
        int r = it*16 + (lane >> 2), u = lane & 3;
        f16x8 vv = *(const f16x8*)(tb + u*512 + r*16);   // 2-way bank aliasing (free)
        *(f16x8*)((char*)dst0 + it*1024 + lane*16) = vv;
      }
    } else {           // v: transposed [b][h][32dd][256n] (lane-consecutive n, 2 lines/instr)
      f16* dst = qkv + 2ull*QSZ + ((size_t)(b_*4 + hh)*32)*256 + n;
      #pragma unroll
      for (int g = 0; g < 4; ++g) {
        #pragma unroll
        for (int i = 0; i < 4; ++i) {
          int dd = g*8 + hi*4 + i;
          dst[(size_t)dd*256] = (f16)acc[g*4 + i];
        }
      }
    }
  }
  // wave partials -> LDS -> single atomic pair per block
  #pragma unroll
  for (int o = 32; o > 0; o >>= 1) { sq += __shfl_xor(sq, o); sk += __shfl_xor(sk, o); }
  __syncthreads();
  float* red = (float*)xs;
  if (lane == 0) { red[wv*2] = sq; red[wv*2 + 1] = sk; }
  __syncthreads();
  if (tid == 0) {
    float a = 0.f, bsum = 0.f;
    #pragma unroll
    for (int i = 0; i < 8; ++i) { a += red[i*2]; bsum += red[i*2 + 1]; }
    float* sl = slots + 2*(blockIdx.x & 63);
    atomicAdd(sl + 0, a);
    atomicAdd(sl + 1, bsum);
  }
}

// ---------------- K4b: reduce 64 slot-pairs -> norms ----------------
__global__ void k_norm(const float* __restrict__ slots, float* __restrict__ norms) {
  int l = threadIdx.x;                           // 64 threads
  float a = slots[2*l], b = slots[2*l + 1];
  #pragma unroll
  for (int o = 32; o > 0; o >>= 1) { a += __shfl_xor(a, o); b += __shfl_xor(b, o); }
  if (l == 0) { norms[0] = a; norms[1] = b; }
}

// ---------------- K5: window attention, block = (window, head), packed-f16 softmax ----------------
// XCD swizzle: blk -> (xcd = blk&7, s = blk>>3), b = (s>>2)*8 + xcd, h = s&3.
// kbuf chunk t (16B): mt=t>>7, ch=(t>>5)&3, l=t&31  holds K[m=mt*32+l][dd=ch*8..+8]
// vbuf chunk t (16B): kc=t>>5, dd=t&31              holds V^T[dd][m=kc*8..+8]
// Tables: wave-coalesced [h|w][g][mt][ln][hi][16f16]: per-mt wave slice = 2 KB contiguous.
// Row-sums computed on the MFMA pipe: mfma(P-frag, ones) -> sacc in oacc layout.
__global__ __launch_bounds__(512, 6)
void k_attn(const f16* __restrict__ qkv, f16* __restrict__ qo,
            const f16* __restrict__ biasp, const f16* __restrict__ maskp,
            const float* __restrict__ norms, const float* __restrict__ taup) {
  __shared__ f16 kbuf[8192];   // 16 KB
  __shared__ f16 vbuf[8192];   // 16 KB

  int blk = blockIdx.x;
  int xcd = blk & 7, s = blk >> 3;
  int b = (s >> 2)*8 + xcd;    // window 0..1023
  int h = s & 3;               // head
  int w = b & 63;
  int tid = threadIdx.x;
  int wv = tid >> 6, lane = tid & 63;
  int ln = lane & 31, hi = lane >> 5;
  int n0 = wv * 32;
  int nrow = n0 + ln;

  float tau = fmaxf(taup[0], 0.01f);
  float scale = LOG2E / (sqrtf(norms[0]) * sqrtf(norms[1]) * tau);
  f16 scale_h = (f16)scale;
  f16x2 s2 = {scale_h, scale_h};

  // q frags (issued before staging; independent vmem)
  const f16* qrow = qkv + (size_t)(b*4 + h)*8192 + (size_t)nrow*32 + hi*8;
  f16x8 qf0 = *(const f16x8*)(qrow);
  f16x8 qf1 = *(const f16x8*)(qrow + 16);

  { // stage K,V for this head once: 4 global_load_lds x16B per thread
    const char* kg = (const char*)(qkv + QSZ + (size_t)(b*4 + h)*8192);
    const char* vg = (const char*)(qkv + 2ull*QSZ + (size_t)(b*4 + h)*8192);
    #pragma unroll
    for (int it = 0; it < 2; ++it) {
      int t = it*512 + wv*64 + lane;
      int mt_ = t >> 7, ch = (t >> 5) & 3, l = t & 31;
      const char* src = kg + ((mt_*32 + l)*64 + ch*16);
      char* dst = (char*)kbuf + (size_t)(it*512 + wv*64)*16;   // wave-uniform base
      __builtin_amdgcn_global_load_lds((gau32*)src, (lau32*)dst, 16, 0, 0);
    }
    #pragma unroll
    for (int it = 0; it < 2; ++it) {
      int t = it*512 + wv*64 + lane;
      int kc = t >> 5, dd = t & 31;
      const char* src = vg + (dd*512 + kc*16);
      char* dst = (char*)vbuf + (size_t)(it*512 + wv*64)*16;
      __builtin_amdgcn_global_load_lds((gau32*)src, (lau32*)dst, 16, 0, 0);
    }
  }
  __syncthreads();          // staged (compiler drains vmcnt before barrier)

  // wave-coalesced table bases (u32 units); pointer-bumped by 512 u32 per mt
  int g = wv;               // row-group = wave
  const u32* bp = (const u32*)biasp + (size_t)(h*8 + g)*4096 + (ln*2 + hi)*8;
  const u32* mp = (const u32*)maskp + (size_t)w*32768 + (size_t)g*4096 + (ln*2 + hi)*8;

  f32x16 oacc, sacc, zf;
  #pragma unroll
  for (int r = 0; r < 16; ++r) { oacc[r] = 0.f; sacc[r] = 0.f; zf[r] = 0.f; }
  f16x8 ones;
  #pragma unroll
  for (int j = 0; j < 8; ++j) ones[j] = (f16)1.0f;

  #pragma unroll 1
  for (int mt = 0; mt < 8; ++mt) {
    f16x8 ka0 = *(const f16x8*)(kbuf + ((size_t)((mt*4 + hi)*32 + ln))*8);
    f16x8 ka1 = *(const f16x8*)(kbuf + ((size_t)((mt*4 + 2 + hi)*32 + ln))*8);
    f32x16 c = __builtin_amdgcn_mfma_f32_32x32x16_f16(ka0, qf0, zf, 0, 0, 0);  // acc-in = persistent zeros
    c = __builtin_amdgcn_mfma_f32_32x32x16_f16(ka1, qf1, c, 0, 0, 0);

    // packed-f16 softmax: u[j] holds exp2 of logits for c[2j],c[2j+1]
    u32 u[8];
    #pragma unroll
    for (int j = 0; j < 8; ++j) {
      f16x2 bm = __builtin_bit_cast(f16x2, bp[j]) + __builtin_bit_cast(f16x2, mp[j]);
      f16x2 cp = __builtin_bit_cast(f16x2, __builtin_amdgcn_cvt_pkrtz(c[2*j], c[2*j + 1]));
      f16x2 l2 = cp * s2 + bm;                       // v_pk_fma_f16
      __half2 e = h2exp2(__builtin_bit_cast(__half2, l2));   // v_exp_f16 = 2^x
      u[j] = __builtin_bit_cast(u32, e);
    }
    bp += 512; mp += 512;
    // PV + row-sum (MFMA pipe): u's ARE the A-frag words after permlane pairing
    #pragma unroll
    for (int half = 0; half < 2; ++half) {
      u32 q0 = u[half*4 + 0], q1 = u[half*4 + 1], q2 = u[half*4 + 2], q3 = u[half*4 + 3];
      asm volatile("v_permlane32_swap_b32 %0, %1" : "+v"(q0), "+v"(q2));
      asm volatile("v_permlane32_swap_b32 %0, %1" : "+v"(q1), "+v"(q3));
      u32x4 av; av[0] = q0; av[1] = q1; av[2] = q2; av[3] = q3;
      f16x8 afrag = __builtin_bit_cast(f16x8, av);
      int ks = mt*2 + half;
      f16x8 vfrag = *(const f16x8*)(vbuf + ((size_t)((2*ks + hi)*32 + ln))*8);
      oacc = __builtin_amdgcn_mfma_f32_32x32x16_f16(afrag, vfrag, oacc, 0, 0, 0);
      sacc = __builtin_amdgcn_mfma_f32_32x32x16_f16(afrag, ones, sacc, 0, 0, 0);
    }
  }

  // oacc/sacc share layout: reg r = q-row (r&3)+8*(r>>2)+4*hi. Elementwise normalize.
  f16* ob = qo + (size_t)(b*4 + h)*8192 + (size_t)n0*32 + ln;
  #pragma unroll
  for (int r = 0; r < 16; ++r) {
    int nl = (r & 3) + 8*(r >> 2) + 4*hi;
    float rcp = __builtin_amdgcn_rcpf(sacc[r]);
    ob[nl*32] = (f16)(oacc[r] * rcp);
  }
}

// ---------------- K6: proj GEMM: out = O @ proj_w + b (XCD-swizzled to match k_attn O writes) ----------------
__global__ __launch_bounds__(256, 4)
void k_proj(const f16* __restrict__ O, const f16* __restrict__ pwt,
            const float* __restrict__ projb, float* __restrict__ out) {
  int blk = blockIdx.x;
  int xcd = blk & 7, s = blk >> 3;               // s 0..255
  int window = (s >> 1)*8 + xcd;                 // 0..1023, window&7 == xcd
  int half = s & 1;
  int tid = threadIdx.x;
  int wv = tid >> 6, lane = tid & 63;
  int ln = lane & 31, hi = lane >> 5;
  int row0 = window*256 + half*128 + wv*32;
  int row = row0 + ln;
  int b_ = row >> 8, n = row & 255;

  f16x8 afr[8];
  #pragma unroll
  for (int ks = 0; ks < 8; ++ks) {
    int h = ks >> 1;
    int dd0 = (ks & 1)*16 + hi*8;
    afr[ks] = *(const f16x8*)(O + ((size_t)(b_*4 + h)*256 + n)*32 + dd0);
  }

  #pragma unroll 1
  for (int ct = 0; ct < 4; ++ct) {
    int cout = ct*32 + ln;
    float pb = projb[cout];
    f32x16 pacc;
    #pragma unroll
    for (int r = 0; r < 16; ++r) pacc[r] = pb;
    const f16* prow = pwt + (size_t)cout*128 + hi*8;
    #pragma unroll
    for (int ks = 0; ks < 8; ++ks) {
      f16x8 bfr = *(const f16x8*)(prow + ks*16);
      pacc = __builtin_amdgcn_mfma_f32_32x32x16_f16(afr[ks], bfr, pacc, 0, 0, 0);
    }
    #pragma unroll
    for (int r = 0; r < 16; ++r) {
      int nl = (r & 3) + 8*(r >> 2) + 4*hi;
      out[(size_t)(row0 + nl)*128 + cout] = pacc[r];
    }
  }
}

// ---------------- launch ----------------
extern "C" void kernel_launch(void* const* d_in, const int* in_sizes, int n_in,
                              void* d_out, int out_size, void* d_ws, size_t ws_size,
                              hipStream_t stream) {
  const float* x     = (const float*)d_in[0];
  const float* mask  = (const float*)d_in[1];
  const float* rel   = (const float*)d_in[2];
  const float* qkvw  = (const float*)d_in[3];
  const float* qkvb  = (const float*)d_in[4];
  const float* projw = (const float*)d_in[5];
  const float* projb = (const float*)d_in[6];
  const float* fc1w  = (const float*)d_in[7];
  const float* fc1b  = (const float*)d_in[8];
  const float* fc2w  = (const float*)d_in[9];
  const float* fc2b  = (const float*)d_in[10];
  const float* tau   = (const float*)d_in[11];
  float* outp = (float*)d_out;
  char* ws = (char*)d_ws;

  float* norms  = (float*)(ws + OFF_NORM);
  float* slots  = (float*)(ws + OFF_SLOTS);
  f16*   wt     = (f16*)(ws + OFF_WT);
  f16*   pwt    = (f16*)(ws + OFF_PWT);
  f16*   biasp  = (f16*)(ws + OFF_BIASP);
  f16*   maskp  = (f16*)(ws + OFF_MASKP);
  f16*   qkv    = (f16*)(ws + OFF_QKV);

  (void)hipMemsetAsync(slots, 0, 512, stream);
  k_bias<<<256, 256, 0, stream>>>(rel, fc1w, fc1b, fc2w, fc2b, biasp);
  k_transpose<<<256, 256, 0, stream>>>(qkvw, projw, wt, pwt);
  k_perm<<<1024, 256, 0, stream>>>(mask, maskp);
  k_qkv<<<4096, 512, 0, stream>>>(x, wt, qkvb, qkv, slots);
  k_norm<<<1, 64, 0, stream>>>(slots, norms);
  k_attn<<<4096, 512, 0, stream>>>(qkv, qkv, biasp, maskp, norms, tau);
  k_proj<<<2048, 256, 0, stream>>>(qkv, pwt, projb, outp);
}

// Round 24
// 269.523 us; speedup vs baseline: 1.0153x; 1.0153x over previous
//
#include <hip/hip_runtime.h>
#include <hip/hip_fp16.h>
#include <cstddef>

typedef _Float16 f16;
typedef __attribute__((ext_vector_type(8))) _Float16 f16x8;
typedef __attribute__((ext_vector_type(4))) _Float16 f16x4;
typedef __attribute__((ext_vector_type(2))) _Float16 f16x2;
typedef __attribute__((ext_vector_type(4))) float f32x4;
typedef __attribute__((ext_vector_type(16))) float f32x16;
typedef __attribute__((ext_vector_type(4))) unsigned int u32x4;
typedef unsigned int u32;

#define LOG2E 1.44269504088896340736f

typedef __attribute__((address_space(1))) const unsigned int gau32;
typedef __attribute__((address_space(3))) unsigned int lau32;

// ---------------- workspace layout (bytes) ----------------
#define OFF_NORM  0ull                                // 2 floats (sumsq q, sumsq k)
#define OFF_SLOTS 128ull                              // 64 slot-pairs (spread atomics), 512 B
#define OFF_WT    1024ull                             // f16 wt2[12ct][8ks][32ln][2hi][8] (wave-coalesced)
#define OFF_PWT   (OFF_WT + 384ull*128*2)             // f16 pwt2[4ct][8ks][32ln][2hi][8] (wave-coalesced)
#define OFF_BIASP (OFF_PWT + 128ull*128*2)            // f16 bias2[4h][8g][8mt][32ln][2hi][16] (xLOG2E)
#define OFF_MASKP (OFF_BIASP + 4ull*256*256*2)        // f16 mask2[64w][8g][8mt][32ln][2hi][16] (xLOG2E)
#define OFF_QKV   (OFF_MASKP + 64ull*256*256*2)       // f16 q[1024][4][256][32] (-> overwritten by O), k same, vT[1024][4][32][256]
// end = OFF_QKV + 201,326,592 = 210,371,584 bytes (proven size)

#define QSZ 33554432ull   // elements per q/k/v section

// ---------------- K1: rel-pos bias MLP -> wave-coalesced f16 table (log2e-scaled) ----------------
// B2[h][g][mt][ln][hi][q]: g=n>>5, ln=n&31; m = mt*32 + rq*8 + hi*4 + i, q = rq*4+i.
__global__ void k_bias(const float* __restrict__ rel, const float* __restrict__ fc1w,
                       const float* __restrict__ fc1b, const float* __restrict__ fc2w,
                       const float* __restrict__ fc2b, f16* __restrict__ biasp) {
  int n = blockIdx.x, m = threadIdx.x;
  float r0 = rel[(n*256 + m)*2 + 0];
  float r1 = rel[(n*256 + m)*2 + 1];
  float a0 = fc2b[0], a1 = fc2b[1], a2 = fc2b[2], a3 = fc2b[3];
  for (int i = 0; i < 128; ++i) {
    float h = fmaf(r0, fc1w[i], fmaf(r1, fc1w[128 + i], fc1b[i]));
    float t = tanhf(0.7978845608028654f * (h + 0.044715f * h * h * h));
    float g = 0.5f * h * (1.0f + t);
    a0 = fmaf(g, fc2w[i*4 + 0], a0);
    a1 = fmaf(g, fc2w[i*4 + 1], a1);
    a2 = fmaf(g, fc2w[i*4 + 2], a2);
    a3 = fmaf(g, fc2w[i*4 + 3], a3);
  }
  int g = n >> 5, ln = n & 31;
  int mt = m >> 5, rem = m & 31;
  int rq = rem >> 3, hi = (rem >> 2) & 1, i = rem & 3;
  size_t base = (((size_t)(g*8 + mt)*32 + ln)*2 + hi)*16 + (rq*4 + i);
  biasp[0*65536 + base] = (f16)(a0 * LOG2E);
  biasp[1*65536 + base] = (f16)(a1 * LOG2E);
  biasp[2*65536 + base] = (f16)(a2 * LOG2E);
  biasp[3*65536 + base] = (f16)(a3 * LOG2E);
}

// ---------------- K2: weight transposes (fp32 -> fp16, both wave-coalesced) ----------------
// wt2[(((ct*8+ks)*32+ln)*2+hi)*8 + j] = qkv_w[k][col], col=ct*32+ln, k=ks*16+hi*8+j
// pwt2 same formula over proj_w (4 cts).
__global__ void k_transpose(const float* __restrict__ qkvw, const float* __restrict__ projw,
                            f16* __restrict__ wt, f16* __restrict__ pwt) {
  int idx = blockIdx.x*256 + threadIdx.x;        // 0..65535
  if (idx < 49152) {
    int col = idx >> 7, k = idx & 127;
    int ct = col >> 5, ln = col & 31;
    int ks = k >> 4, hi = (k >> 3) & 1, j = k & 7;
    wt[(((size_t)(ct*8 + ks)*32 + ln)*2 + hi)*8 + j] = (f16)qkvw[k*384 + col];
  } else {
    int p = idx - 49152;
    int col = p >> 7, k = p & 127;
    int ct = col >> 5, ln = col & 31;
    int ks = k >> 4, hi = (k >> 3) & 1, j = k & 7;
    pwt[(((size_t)(ct*8 + ks)*32 + ln)*2 + hi)*8 + j] = (f16)projw[k*128 + col];
  }
}

// ---------------- K3: mask fp32 -> wave-coalesced f16 (log2e-scaled) ----------------
__global__ void k_perm(const float* __restrict__ mask, f16* __restrict__ maskp) {
  int t = blockIdx.x*256 + threadIdx.x;          // 0..262143
  int mt = t & 7, hi = (t >> 3) & 1, n = (t >> 4) & 255, w = t >> 12;
  int g = n >> 5, ln = n & 31;
  const float* src = mask + (size_t)(w*256 + n)*256;
  f16* dst = maskp + (size_t)w*65536 + (((size_t)(g*8 + mt)*32 + ln)*2 + hi)*16;
  #pragma unroll
  for (int rq = 0; rq < 4; ++rq) {
    f32x4 v = *(const f32x4*)(src + mt*32 + rq*8 + hi*4);
    #pragma unroll
    for (int i = 0; i < 4; ++i) dst[rq*4 + i] = (f16)(v[i] * LOG2E);
  }
}

// ---------------- K4: QKV GEMM, 4096 blocks x 512 thr (unchanged from r21) ----------------
__global__ __launch_bounds__(512, 6)
void k_qkv(const float* __restrict__ x, const f16* __restrict__ wt,
           const float* __restrict__ qkvb, f16* __restrict__ qkv,
           float* __restrict__ slots) {
  __shared__ f16 xs[8192];
  int tid = threadIdx.x;
  int wv = tid >> 6, lane = tid & 63;
  int ln = lane & 31, hi = lane >> 5;

  {
    const float* xt = x + (size_t)blockIdx.x*8192;
    char* xw = (char*)xs;
    #pragma unroll
    for (int it = 0; it < 4; ++it) {
      int idx = it*2048 + tid*4;
      int rowl = idx >> 7, col = idx & 127;
      f32x4 v = *(const f32x4*)(xt + idx);
      f16x4 hv;
      #pragma unroll
      for (int j = 0; j < 4; ++j) hv[j] = (f16)v[j];
      *(f16x4*)(xw + rowl*256 + ((col*2) ^ ((rowl & 15) << 4))) = hv;
    }
  }
  __syncthreads();

  int rl = (wv >> 2)*32 + ln;
  int row = blockIdx.x*64 + rl;
  int b_ = row >> 8, n = row & 255;
  int ct0 = (wv & 3)*3;

  f16x8 xf[8];
  {
    const char* xw = (const char*)xs;
    #pragma unroll
    for (int ks = 0; ks < 8; ++ks)
      xf[ks] = *(const f16x8*)(xw + rl*256 + ((ks*32 + hi*16) ^ ((rl & 15) << 4)));
  }
  __syncthreads();

  char* tb = (char*)xs + wv*2048;
  int nb0 = blockIdx.x*64 + (wv >> 2)*32;
  int b2 = nb0 >> 8, n2 = nb0 & 255;

  float sq = 0.f, sk = 0.f;
  #pragma unroll 1
  for (int cc = 0; cc < 3; ++cc) {
    int ct = ct0 + cc;
    f32x16 acc;
    #pragma unroll
    for (int g = 0; g < 4; ++g) {
      f32x4 qb = *(const f32x4*)(qkvb + ct*32 + g*8 + hi*4);
      #pragma unroll
      for (int i = 0; i < 4; ++i) acc[g*4 + i] = qb[i];
    }
    const f16* wbase = wt + (size_t)(ct*8)*512 + (ln*2 + hi)*8;
    #pragma unroll
    for (int ks = 0; ks < 8; ++ks) {
      f16x8 wf = *(const f16x8*)(wbase + ks*512);
      acc = __builtin_amdgcn_mfma_f32_32x32x16_f16(wf, xf[ks], acc, 0, 0, 0);
    }
    int which = ct >> 2, hh = ct & 3;
    if (which == 0) {
      #pragma unroll
      for (int r = 0; r < 16; ++r) sq = fmaf(acc[r], acc[r], sq);
    } else if (which == 1) {
      #pragma unroll
      for (int r = 0; r < 16; ++r) sk = fmaf(acc[r], acc[r], sk);
    }
    if (which < 2) {
      #pragma unroll
      for (int g = 0; g < 4; ++g) {
        f16x4 pk;
        #pragma unroll
        for (int i = 0; i < 4; ++i) pk[i] = (f16)acc[g*4 + i];
        *(f16x4*)(tb + g*512 + ln*16 + hi*8) = pk;
      }
      f16* dst0 = qkv + (size_t)which*QSZ + ((size_t)(b2*4 + hh)*256 + n2)*32;
      #pragma unroll
      for (int it = 0; it < 2; ++it) {
        int r = it*16 + (lane >> 2), u = lane & 3;
        f16x8 vv = *(const f16x8*)(tb + u*512 + r*16);
        *(f16x8*)((char*)dst0 + it*1024 + lane*16) = vv;
      }
    } else {
      f16* dst = qkv + 2ull*QSZ + ((size_t)(b_*4 + hh)*32)*256 + n;
      #pragma unroll
      for (int g = 0; g < 4; ++g) {
        #pragma unroll
        for (int i = 0; i < 4; ++i) {
          int dd = g*8 + hi*4 + i;
          dst[(size_t)dd*256] = (f16)acc[g*4 + i];
        }
      }
    }
  }
  #pragma unroll
  for (int o = 32; o > 0; o >>= 1) { sq += __shfl_xor(sq, o); sk += __shfl_xor(sk, o); }
  __syncthreads();
  float* red = (float*)xs;
  if (lane == 0) { red[wv*2] = sq; red[wv*2 + 1] = sk; }
  __syncthreads();
  if (tid == 0) {
    float a = 0.f, bsum = 0.f;
    #pragma unroll
    for (int i = 0; i < 8; ++i) { a += red[i*2]; bsum += red[i*2 + 1]; }
    float* sl = slots + 2*(blockIdx.x & 63);
    atomicAdd(sl + 0, a);
    atomicAdd(sl + 1, bsum);
  }
}

// ---------------- K4b: reduce 64 slot-pairs -> norms ----------------
__global__ void k_norm(const float* __restrict__ slots, float* __restrict__ norms) {
  int l = threadIdx.x;
  float a = slots[2*l], b = slots[2*l + 1];
  #pragma unroll
  for (int o = 32; o > 0; o >>= 1) { a += __shfl_xor(a, o); b += __shfl_xor(b, o); }
  if (l == 0) { norms[0] = a; norms[1] = b; }
}

// ---------------- K5: window attention (unchanged from r23) ----------------
__global__ __launch_bounds__(512, 6)
void k_attn(const f16* __restrict__ qkv, f16* __restrict__ qo,
            const f16* __restrict__ biasp, const f16* __restrict__ maskp,
            const float* __restrict__ norms, const float* __restrict__ taup) {
  __shared__ f16 kbuf[8192];
  __shared__ f16 vbuf[8192];

  int blk = blockIdx.x;
  int xcd = blk & 7, s = blk >> 3;
  int b = (s >> 2)*8 + xcd;
  int h = s & 3;
  int w = b & 63;
  int tid = threadIdx.x;
  int wv = tid >> 6, lane = tid & 63;
  int ln = lane & 31, hi = lane >> 5;
  int n0 = wv * 32;
  int nrow = n0 + ln;

  float tau = fmaxf(taup[0], 0.01f);
  float scale = LOG2E / (sqrtf(norms[0]) * sqrtf(norms[1]) * tau);
  f16 scale_h = (f16)scale;
  f16x2 s2 = {scale_h, scale_h};

  const f16* qrow = qkv + (size_t)(b*4 + h)*8192 + (size_t)nrow*32 + hi*8;
  f16x8 qf0 = *(const f16x8*)(qrow);
  f16x8 qf1 = *(const f16x8*)(qrow + 16);

  {
    const char* kg = (const char*)(qkv + QSZ + (size_t)(b*4 + h)*8192);
    const char* vg = (const char*)(qkv + 2ull*QSZ + (size_t)(b*4 + h)*8192);
    #pragma unroll
    for (int it = 0; it < 2; ++it) {
      int t = it*512 + wv*64 + lane;
      int mt_ = t >> 7, ch = (t >> 5) & 3, l = t & 31;
      const char* src = kg + ((mt_*32 + l)*64 + ch*16);
      char* dst = (char*)kbuf + (size_t)(it*512 + wv*64)*16;
      __builtin_amdgcn_global_load_lds((gau32*)src, (lau32*)dst, 16, 0, 0);
    }
    #pragma unroll
    for (int it = 0; it < 2; ++it) {
      int t = it*512 + wv*64 + lane;
      int kc = t >> 5, dd = t & 31;
      const char* src = vg + (dd*512 + kc*16);
      char* dst = (char*)vbuf + (size_t)(it*512 + wv*64)*16;
      __builtin_amdgcn_global_load_lds((gau32*)src, (lau32*)dst, 16, 0, 0);
    }
  }
  __syncthreads();

  int g = wv;
  const u32* bp = (const u32*)biasp + (size_t)(h*8 + g)*4096 + (ln*2 + hi)*8;
  const u32* mp = (const u32*)maskp + (size_t)w*32768 + (size_t)g*4096 + (ln*2 + hi)*8;

  f32x16 oacc, sacc, zf;
  #pragma unroll
  for (int r = 0; r < 16; ++r) { oacc[r] = 0.f; sacc[r] = 0.f; zf[r] = 0.f; }
  f16x8 ones;
  #pragma unroll
  for (int j = 0; j < 8; ++j) ones[j] = (f16)1.0f;

  #pragma unroll 1
  for (int mt = 0; mt < 8; ++mt) {
    f16x8 ka0 = *(const f16x8*)(kbuf + ((size_t)((mt*4 + hi)*32 + ln))*8);
    f16x8 ka1 = *(const f16x8*)(kbuf + ((size_t)((mt*4 + 2 + hi)*32 + ln))*8);
    f32x16 c = __builtin_amdgcn_mfma_f32_32x32x16_f16(ka0, qf0, zf, 0, 0, 0);
    c = __builtin_amdgcn_mfma_f32_32x32x16_f16(ka1, qf1, c, 0, 0, 0);

    u32 u[8];
    #pragma unroll
    for (int j = 0; j < 8; ++j) {
      f16x2 bm = __builtin_bit_cast(f16x2, bp[j]) + __builtin_bit_cast(f16x2, mp[j]);
      f16x2 cp = __builtin_bit_cast(f16x2, __builtin_amdgcn_cvt_pkrtz(c[2*j], c[2*j + 1]));
      f16x2 l2 = cp * s2 + bm;
      __half2 e = h2exp2(__builtin_bit_cast(__half2, l2));
      u[j] = __builtin_bit_cast(u32, e);
    }
    bp += 512; mp += 512;
    #pragma unroll
    for (int half = 0; half < 2; ++half) {
      u32 q0 = u[half*4 + 0], q1 = u[half*4 + 1], q2 = u[half*4 + 2], q3 = u[half*4 + 3];
      asm volatile("v_permlane32_swap_b32 %0, %1" : "+v"(q0), "+v"(q2));
      asm volatile("v_permlane32_swap_b32 %0, %1" : "+v"(q1), "+v"(q3));
      u32x4 av; av[0] = q0; av[1] = q1; av[2] = q2; av[3] = q3;
      f16x8 afrag = __builtin_bit_cast(f16x8, av);
      int ks = mt*2 + half;
      f16x8 vfrag = *(const f16x8*)(vbuf + ((size_t)((2*ks + hi)*32 + ln))*8);
      oacc = __builtin_amdgcn_mfma_f32_32x32x16_f16(afrag, vfrag, oacc, 0, 0, 0);
      sacc = __builtin_amdgcn_mfma_f32_32x32x16_f16(afrag, ones, sacc, 0, 0, 0);
    }
  }

  f16* ob = qo + (size_t)(b*4 + h)*8192 + (size_t)n0*32 + ln;
  #pragma unroll
  for (int r = 0; r < 16; ++r) {
    int nl = (r & 3) + 8*(r >> 2) + 4*hi;
    float rcp = __builtin_amdgcn_rcpf(sacc[r]);
    ob[nl*32] = (f16)(oacc[r] * rcp);
  }
}

// ---------------- K6: proj GEMM with LDS-staged O (r20 pattern) ----------------
// 2048 blocks x 256 thr; block = 128 rows of one window-half. O tile (128x128 f16, 32 KB)
// staged coalesced (per-head 8 KB contiguous chunks), XOR-swizzled; pwt2 1KB-coalesced B loads.
__global__ __launch_bounds__(256, 4)
void k_proj(const f16* __restrict__ O, const f16* __restrict__ pwt,
            const float* __restrict__ projb, float* __restrict__ out) {
  __shared__ f16 os[16384];   // [128 row][128 c] f16 swizzled: byte = row*256 + ((c*2) ^ ((row&15)<<4))
  int blk = blockIdx.x;
  int xcd = blk & 7, s = blk >> 3;               // s 0..255
  int window = (s >> 1)*8 + xcd;                 // 0..1023, window&7 == xcd
  int half = s & 1;
  int tid = threadIdx.x;
  int wv = tid >> 6, lane = tid & 63;
  int ln = lane & 31, hi = lane >> 5;

  // cooperative stage: 128x128 O tile (4 heads x [128 n][32 dd] contiguous 8KB chunks)
  {
    const char* obase = (const char*)(O + ((size_t)window*4*256 + half*128)*32);
    char* ow = (char*)os;
    #pragma unroll
    for (int it = 0; it < 8; ++it) {
      int flat = it*4096 + tid*16;               // byte in 32 KB tile
      int h = flat >> 13;                        // head chunk (8 KB each)
      int rem = flat & 8191;
      int nloc = rem >> 6;                       // row within 128 (64 B per row-chunk)
      int db = rem & 63;                         // byte within row's 32-dd slice
      f16x8 v = *(const f16x8*)(obase + (size_t)h*16384 + nloc*64 + db);
      int cb = h*64 + db;                        // byte col in [128 c]
      *(f16x8*)(ow + nloc*256 + (cb ^ ((nloc & 15) << 4))) = v;
    }
  }
  __syncthreads();

  int rl = wv*32 + ln;                           // local row (0..127)
  int row0 = window*256 + half*128 + wv*32;

  // A-frags from swizzled LDS (conflict-free, same recipe as k_qkv)
  f16x8 afr[8];
  {
    const char* ow = (const char*)os;
    #pragma unroll
    for (int ks = 0; ks < 8; ++ks)
      afr[ks] = *(const f16x8*)(ow + rl*256 + ((ks*32 + hi*16) ^ ((rl & 15) << 4)));
  }

  #pragma unroll 1
  for (int ct = 0; ct < 4; ++ct) {
    int cout = ct*32 + ln;
    float pb = projb[cout];
    f32x16 pacc;
    #pragma unroll
    for (int r = 0; r < 16; ++r) pacc[r] = pb;
    const f16* pbase = pwt + (size_t)(ct*8)*512 + (ln*2 + hi)*8;
    #pragma unroll
    for (int ks = 0; ks < 8; ++ks) {
      f16x8 bfr = *(const f16x8*)(pbase + ks*512);   // 1KB coalesced
      pacc = __builtin_amdgcn_mfma_f32_32x32x16_f16(afr[ks], bfr, pacc, 0, 0, 0);
    }
    #pragma unroll
    for (int r = 0; r < 16; ++r) {
      int nl = (r & 3) + 8*(r >> 2) + 4*hi;
      out[(size_t)(row0 + nl)*128 + cout] = pacc[r];
    }
  }
}

// ---------------- launch ----------------
extern "C" void kernel_launch(void* const* d_in, const int* in_sizes, int n_in,
                              void* d_out, int out_size, void* d_ws, size_t ws_size,
                              hipStream_t stream) {
  const float* x     = (const float*)d_in[0];
  const float* mask  = (const float*)d_in[1];
  const float* rel   = (const float*)d_in[2];
  const float* qkvw  = (const float*)d_in[3];
  const float* qkvb  = (const float*)d_in[4];
  const float* projw = (const float*)d_in[5];
  const float* projb = (const float*)d_in[6];
  const float* fc1w  = (const float*)d_in[7];
  const float* fc1b  = (const float*)d_in[8];
  const float* fc2w  = (const float*)d_in[9];
  const float* fc2b  = (const float*)d_in[10];
  const float* tau   = (const float*)d_in[11];
  float* outp = (float*)d_out;
  char* ws = (char*)d_ws;

  float* norms  = (float*)(ws + OFF_NORM);
  float* slots  = (float*)(ws + OFF_SLOTS);
  f16*   wt     = (f16*)(ws + OFF_WT);
  f16*   pwt    = (f16*)(ws + OFF_PWT);
  f16*   biasp  = (f16*)(ws + OFF_BIASP);
  f16*   maskp  = (f16*)(ws + OFF_MASKP);
  f16*   qkv    = (f16*)(ws + OFF_QKV);

  (void)hipMemsetAsync(slots, 0, 512, stream);
  k_bias<<<256, 256, 0, stream>>>(rel, fc1w, fc1b, fc2w, fc2b, biasp);
  k_transpose<<<256, 256, 0, stream>>>(qkvw, projw, wt, pwt);
  k_perm<<<1024, 256, 0, stream>>>(mask, maskp);
  k_qkv<<<4096, 512, 0, stream>>>(x, wt, qkvb, qkv, slots);
  k_norm<<<1, 64, 0, stream>>>(slots, norms);
  k_attn<<<4096, 512, 0, stream>>>(qkv, qkv, biasp, maskp, norms, tau);
  k_proj<<<2048, 256, 0, stream>>>(qkv, pwt, projb, outp);
}